// Round 3
// baseline (85.776 us; speedup 1.0000x reference)
//
#include <hip/hip_runtime.h>
#include <math.h>

#define BB 2
#define CC 16
#define HH 32
#define WW 32
#define NN (HH*WW)
#define CHUNK 256          // k's per block
#define NCHUNK (NN/CHUNK)  // 4
#define NPX (BB*NN)        // 2048 pixels

// ---------------------------------------------------------------------------
// Kernel 1: per-(b,k) precompute into ONE packed 128B record (8 float4):
//   slot0..3 : e[0..15]            (embedding, transposed)
//   slot4    : X, Y, Z, p0         (unprojected xyz; p* = pie(T_k x_k)+rev)
//   slot5    : p1, p2, w0, w1
//   slot6    : w2, |e|^2, 0, 0
//   slot7    : pad
// ---------------------------------------------------------------------------
__global__ __launch_bounds__(256)
void dse3_prep2(const float* __restrict__ emb,
                const float* __restrict__ rev,
                const float* __restrict__ wgt,
                const float* __restrict__ dep,
                const float* __restrict__ pix,
                const float* __restrict__ Tm,
                float* __restrict__ kd2)
{
    int idx = blockIdx.x * 256 + threadIdx.x;
    if (idx >= NPX) return;
    int b = idx >> 10;
    int k = idx & (NN - 1);

    float fx = pix[b*16 + 0], fy = pix[b*16 + 5];
    float x0 = pix[b*16 + 2], y0 = pix[b*16 + 6];

    float u = (float)(k & (WW - 1));
    float v = (float)(k >> 5);
    float z = dep[b*NN + k];
    float X = (u - x0) * z / fx;
    float Y = (v - y0) * z / fy;

    const float* T = Tm + (size_t)idx * 16;
    float Tx = T[0]*X + T[1]*Y + T[2]*z  + T[3];
    float Ty = T[4]*X + T[5]*Y + T[6]*z  + T[7];
    float Tz = T[8]*X + T[9]*Y + T[10]*z + T[11];
    float di = 1.0f / Tz;

    float p0 = fx*Tx*di + x0 + rev[(size_t)b*3*NN + 0*NN + k];
    float p1 = fy*Ty*di + y0 + rev[(size_t)b*3*NN + 1*NN + k];
    float p2 = di            + rev[(size_t)b*3*NN + 2*NN + k];
    float w0 = wgt[(size_t)b*3*NN + 0*NN + k];
    float w1 = wgt[(size_t)b*3*NN + 1*NN + k];
    float w2 = wgt[(size_t)b*3*NN + 2*NN + k];

    float se = 0.f;
    float ev[16];
    #pragma unroll
    for (int c = 0; c < 16; ++c) {
        ev[c] = emb[(size_t)b*CC*NN + (size_t)c*NN + k];
        se += ev[c]*ev[c];
    }

    float4* op = (float4*)kd2 + (size_t)idx * 8;
    #pragma unroll
    for (int c4 = 0; c4 < 4; ++c4)
        op[c4] = make_float4(ev[c4*4+0], ev[c4*4+1], ev[c4*4+2], ev[c4*4+3]);
    op[4] = make_float4(X, Y, z, p0);
    op[5] = make_float4(p1, p2, w0, w1);
    op[6] = make_float4(w2, se, 0.f, 0.f);
    op[7] = make_float4(0.f, 0.f, 0.f, 0.f);
}

// ---------------------------------------------------------------------------
// Kernel 2: block = 256 thr = 4 waves = 4 pixels x one 256-k chunk.
// Stage chunk (32 KB) into LDS: linear coalesced global float4 reads,
// XOR-swizzled writes (slot ^= row&7) -> conflict-free ds_read_b128.
// Each wave: lane-parallel over k, butterfly-reduce 27 accumulators,
// lane 0 stores the partial in transposed [chunk*27+t][px] layout.
// ---------------------------------------------------------------------------
__global__ __launch_bounds__(256, 5)
void dse3_accum3(const float* __restrict__ kd2,
                 const float* __restrict__ pix,
                 const float* __restrict__ Tm,
                 float* __restrict__ pws)
{
    __shared__ float4 lds4[CHUNK * 8];   // 32 KB

    int tid   = threadIdx.x;
    int lane  = tid & 63;
    int wv    = tid >> 6;
    int chunk = blockIdx.x & (NCHUNK - 1);
    int px    = ((blockIdx.x >> 2) << 2) + wv;   // 4 pixels per block
    int b     = px >> 10;

    // ---- cooperative stage: fully coalesced reads, swizzled LDS writes ----
    {
        const float4* src = (const float4*)kd2
                          + ((size_t)b*NN + (size_t)chunk*CHUNK) * 8;
        #pragma unroll
        for (int s = 0; s < 8; ++s) {
            int g   = s*256 + tid;        // flat float4 idx in chunk (0..2047)
            int row = g >> 3;
            int slot= g & 7;
            lds4[row*8 + (slot ^ (row & 7))] = src[g];
        }
    }

    // ---- per-wave (per-pixel) broadcast data ----
    float fx = pix[b*16 + 0], fy = pix[b*16 + 5];
    float x0 = pix[b*16 + 2], y0 = pix[b*16 + 6];

    const float4* ip = (const float4*)kd2 + (size_t)px * 8;
    float4 e0 = ip[0], e1 = ip[1], e2 = ip[2], e3 = ip[3];
    float  sei = ip[6].y;

    const float* Ti = Tm + (size_t)px * 16;
    float R00=Ti[0], R01=Ti[1], R02=Ti[2],  t0=Ti[3];
    float R10=Ti[4], R11=Ti[5], R12=Ti[6],  t1=Ti[7];
    float R20=Ti[8], R21=Ti[9], R22=Ti[10], t2=Ti[11];

    float acc[27];
    #pragma unroll
    for (int t = 0; t < 27; ++t) acc[t] = 0.f;

    __syncthreads();

    #pragma unroll
    for (int j = 0; j < CHUNK/64; ++j) {
        int row = j*64 + lane;
        const float4* rp = lds4 + row*8;
        int sw = lane & 7;                 // row&7 == lane&7 (64%8==0)

        float4 k0 = rp[0^sw], k1 = rp[1^sw], k2 = rp[2^sw], k3 = rp[3^sw];
        float4 q0 = rp[4^sw], q1 = rp[5^sw], q2 = rp[6^sw];

        // affinity via Gram trick (tree-summed dot)
        float d0 = k0.x*e0.x + k0.y*e0.y + k0.z*e0.z + k0.w*e0.w;
        float d1 = k1.x*e1.x + k1.y*e1.y + k1.z*e1.z + k1.w*e1.w;
        float d2 = k2.x*e2.x + k2.y*e2.y + k2.z*e2.z + k2.w*e2.w;
        float d3 = k3.x*e3.x + k3.y*e3.y + k3.z*e3.z + k3.w*e3.w;
        float dot = (d0 + d1) + (d2 + d3);
        float ssq = fmaxf(sei + q2.y - 2.f*dot, 0.f);
        float aff = __expf(-__builtin_amdgcn_sqrtf(ssq));

        float X = q0.x, Y = q0.y, Z = q0.z;
        float Tx = R00*X + R01*Y + R02*Z + t0;
        float Ty = R10*X + R11*Y + R12*Z + t1;
        float Tz = R20*X + R21*Y + R22*Z + t2;
        float di = __builtin_amdgcn_rcpf(Tz);

        float r0 = fx*Tx*di + x0 - q0.w;
        float r1 = fy*Ty*di + y0 - q1.x;
        float r2 = di            - q1.y;

        float dd = di*di;
        float aJ =  fx*di;
        float cJ = -fx*Tx*dd;
        float eJ =  fy*di;
        float fJ = -fy*Ty*dd;
        float gJ = -dd;

        float J0[6] = { aJ, 0.f, cJ, -cJ*Y,        cJ*X - aJ*Z,  aJ*Y };
        float J1[6] = { 0.f, eJ, fJ,  eJ*Z - fJ*Y, fJ*X,        -eJ*X };
        float J2[6] = { 0.f, 0.f, gJ, -gJ*Y,       gJ*X,         0.f  };

        #pragma unroll
        for (int p = 0; p < 6; ++p)
            acc[21 + p] += J0[p]*r0 + J1[p]*r1 + J2[p]*r2;

        float ww0 = aff*q1.z, ww1 = aff*q1.w, ww2 = aff*q2.x;
        int ix = 0;
        #pragma unroll
        for (int p = 0; p < 6; ++p) {
            float a0 = ww0*J0[p], a1 = ww1*J1[p], a2 = ww2*J2[p];
            #pragma unroll
            for (int q = p; q < 6; ++q) {
                acc[ix] += a0*J0[q] + a1*J1[q] + a2*J2[q];
                ++ix;
            }
        }
    }

    // ---- wave butterfly reduce ----
    #pragma unroll
    for (int off = 32; off > 0; off >>= 1)
        #pragma unroll
        for (int t = 0; t < 27; ++t)
            acc[t] += __shfl_xor(acc[t], off, 64);

    if (lane == 0) {
        #pragma unroll
        for (int t = 0; t < 27; ++t)
            pws[(size_t)(chunk*27 + t)*NPX + px] = acc[t];
    }
}

// ---------------------------------------------------------------------------
// Kernel 3: one thread per pixel. Sum 4 chunk-partials (coalesced reads),
// 6x6 double Cholesky, expmap, compose with Tmat.
// ---------------------------------------------------------------------------
__global__ __launch_bounds__(256)
void dse3_solve2(const float* __restrict__ pws,
                 const float* __restrict__ Tm,
                 float* __restrict__ out)
{
    int px = blockIdx.x * 256 + threadIdx.x;
    if (px >= NPX) return;

    float Hm[21], rh[6];
    #pragma unroll
    for (int t = 0; t < 21; ++t) {
        float s = 0.f;
        #pragma unroll
        for (int c = 0; c < NCHUNK; ++c)
            s += pws[(size_t)(c*27 + t)*NPX + px];
        Hm[t] = s;
    }
    #pragma unroll
    for (int t = 0; t < 6; ++t) {
        float s = 0.f;
        #pragma unroll
        for (int c = 0; c < NCHUNK; ++c)
            s += pws[(size_t)(c*27 + 21 + t)*NPX + px];
        rh[t] = s;
    }

    double am[6][6];
    {
        int ix = 0;
        #pragma unroll
        for (int p = 0; p < 6; ++p)
            #pragma unroll
            for (int q = p; q < 6; ++q) {
                am[p][q] = (double)Hm[ix];
                am[q][p] = (double)Hm[ix];
                ++ix;
            }
    }
    double L[6][6];
    #pragma unroll
    for (int p = 0; p < 6; ++p) {
        #pragma unroll
        for (int q = 0; q <= p; ++q) {
            double s = am[p][q];
            #pragma unroll
            for (int r = 0; r < q; ++r) s -= L[p][r]*L[q][r];
            if (q == p) L[p][p] = sqrt(s);
            else        L[p][q] = s / L[q][q];
        }
    }
    double yv[6];
    #pragma unroll
    for (int p = 0; p < 6; ++p) {
        double s = (double)rh[p];
        #pragma unroll
        for (int r = 0; r < p; ++r) s -= L[p][r]*yv[r];
        yv[p] = s / L[p][p];
    }
    double sol[6];
    #pragma unroll
    for (int pi = 5; pi >= 0; --pi) {
        double s = yv[pi];
        #pragma unroll
        for (int r = pi + 1; r < 6; ++r) s -= L[r][pi]*sol[r];
        sol[pi] = s / L[pi][pi];
    }

    double vx = sol[0], vy = sol[1], vz = sol[2];
    double wx = sol[3], wy = sol[4], wz = sol[5];
    double th2 = wx*wx + wy*wy + wz*wz;
    double th  = sqrt(th2);
    double Ae, Be, Ce;
    if (th < 1e-4) {
        Ae = 1.0 - th2/6.0;
        Be = 0.5 - th2/24.0;
        Ce = 1.0/6.0 - th2/120.0;
    } else {
        double sn = sin(th), cn = cos(th);
        Ae = sn/th;
        Be = (1.0 - cn)/th2;
        Ce = (th - sn)/(th2*th);
    }
    double Wh[3][3] = {{0.0,-wz, wy},{ wz,0.0,-wx},{-wy, wx,0.0}};
    double W2[3][3] = {{wx*wx - th2, wx*wy,       wx*wz      },
                       {wx*wy,       wy*wy - th2, wy*wz      },
                       {wx*wz,       wy*wz,       wz*wz - th2}};
    double Rd[3][3], Vd[3][3];
    #pragma unroll
    for (int p = 0; p < 3; ++p)
        #pragma unroll
        for (int q = 0; q < 3; ++q) {
            double idq = (p == q) ? 1.0 : 0.0;
            Rd[p][q] = idq + Ae*Wh[p][q] + Be*W2[p][q];
            Vd[p][q] = idq + Be*Wh[p][q] + Ce*W2[p][q];
        }
    double td[3];
    #pragma unroll
    for (int p = 0; p < 3; ++p)
        td[p] = Vd[p][0]*vx + Vd[p][1]*vy + Vd[p][2]*vz;

    const float* Ti = Tm + (size_t)px * 16;
    float* o = out + (size_t)px * 16;
    #pragma unroll
    for (int p = 0; p < 3; ++p) {
        #pragma unroll
        for (int q = 0; q < 4; ++q) {
            double s = Rd[p][0]*(double)Ti[q]
                     + Rd[p][1]*(double)Ti[4 + q]
                     + Rd[p][2]*(double)Ti[8 + q]
                     + td[p]   *(double)Ti[12 + q];
            o[p*4 + q] = (float)s;
        }
    }
    #pragma unroll
    for (int q = 0; q < 4; ++q) o[12 + q] = Ti[12 + q];
}

extern "C" void kernel_launch(void* const* d_in, const int* in_sizes, int n_in,
                              void* d_out, int out_size, void* d_ws, size_t ws_size,
                              hipStream_t stream) {
    const float* emb = (const float*)d_in[0];  // (B,C,H,W)
    const float* rev = (const float*)d_in[1];  // (B,3,H,W)
    const float* wgt = (const float*)d_in[2];  // (B,3,H,W)
    const float* dep = (const float*)d_in[3];  // (B,1,H,W)
    const float* pix = (const float*)d_in[4];  // (B,4,4)
    const float* Tm  = (const float*)d_in[5];  // (B,H,W,4,4)
    float* out = (float*)d_out;                // (B,H,W,4,4)

    float* kd2 = (float*)d_ws;                         // NPX*32 floats (256 KB)
    float* pws = kd2 + (size_t)NPX*32;                 // NCHUNK*27*NPX (884 KB)

    dse3_prep2 <<<NPX/256, 256, 0, stream>>>(emb, rev, wgt, dep, pix, Tm, kd2);
    dse3_accum3<<<(NPX/4)*NCHUNK, 256, 0, stream>>>(kd2, pix, Tm, pws);
    dse3_solve2<<<NPX/256, 256, 0, stream>>>(pws, Tm, out);
}

// Round 4
// 36.465 us; speedup vs baseline: 2.3523x; 2.3523x over previous
//
#include <hip/hip_runtime.h>
#include <math.h>

#define BB 2
#define CC 16
#define HH 32
#define WW 32
#define NN (HH*WW)
#define NPX (BB*NN)        // 2048 pixels

// SoA k-record arrays (each float4[NPX]):
//   E0..E3 : embedding e[0..15]
//   Q0     : X, Y, Z, p0      (unprojected xyz; p* = pie(T_k x_k)+rev_k)
//   Q1     : p1, p2, w0, w1
//   Q2     : w2, |e|^2, 0, 0

// ---------------------------------------------------------------------------
// Kernel 1: per-(b,k) precompute into SoA arrays (coalesced writes).
// ---------------------------------------------------------------------------
__global__ __launch_bounds__(256)
void dse3_prep3(const float* __restrict__ emb,
                const float* __restrict__ rev,
                const float* __restrict__ wgt,
                const float* __restrict__ dep,
                const float* __restrict__ pix,
                const float* __restrict__ Tm,
                float4* __restrict__ soa)   // 7 arrays of NPX float4
{
    int idx = blockIdx.x * 256 + threadIdx.x;
    if (idx >= NPX) return;
    int b = idx >> 10;
    int k = idx & (NN - 1);

    float fx = pix[b*16 + 0], fy = pix[b*16 + 5];
    float x0 = pix[b*16 + 2], y0 = pix[b*16 + 6];

    float u = (float)(k & (WW - 1));
    float v = (float)(k >> 5);
    float z = dep[b*NN + k];
    float X = (u - x0) * z / fx;
    float Y = (v - y0) * z / fy;

    const float* T = Tm + (size_t)idx * 16;
    float Tx = T[0]*X + T[1]*Y + T[2]*z  + T[3];
    float Ty = T[4]*X + T[5]*Y + T[6]*z  + T[7];
    float Tz = T[8]*X + T[9]*Y + T[10]*z + T[11];
    float di = 1.0f / Tz;

    float p0 = fx*Tx*di + x0 + rev[(size_t)b*3*NN + 0*NN + k];
    float p1 = fy*Ty*di + y0 + rev[(size_t)b*3*NN + 1*NN + k];
    float p2 = di            + rev[(size_t)b*3*NN + 2*NN + k];
    float w0 = wgt[(size_t)b*3*NN + 0*NN + k];
    float w1 = wgt[(size_t)b*3*NN + 1*NN + k];
    float w2 = wgt[(size_t)b*3*NN + 2*NN + k];

    float se = 0.f;
    float ev[16];
    #pragma unroll
    for (int c = 0; c < 16; ++c) {
        ev[c] = emb[(size_t)b*CC*NN + (size_t)c*NN + k];
        se += ev[c]*ev[c];
    }

    #pragma unroll
    for (int c4 = 0; c4 < 4; ++c4)
        soa[(size_t)c4*NPX + idx] =
            make_float4(ev[c4*4+0], ev[c4*4+1], ev[c4*4+2], ev[c4*4+3]);
    soa[(size_t)4*NPX + idx] = make_float4(X, Y, z, p0);
    soa[(size_t)5*NPX + idx] = make_float4(p1, p2, w0, w1);
    soa[(size_t)6*NPX + idx] = make_float4(w2, se, 0.f, 0.f);
}

// ---------------------------------------------------------------------------
// Kernel 2: block = 256 thr = 4 waves = 2 pixels x 2 waves each.
// Wave handles 512 k's (8 iters x 64 lanes); all loads coalesced (SoA).
// Butterfly reduce 27 accumulators, 2-wave LDS combine, write hws[px*27+t].
// ---------------------------------------------------------------------------
__global__ __launch_bounds__(256)
void dse3_accum4(const float4* __restrict__ soa,
                 const float* __restrict__ pix,
                 const float* __restrict__ Tm,
                 float* __restrict__ hws)
{
    __shared__ float lds[4][27];
    int tid  = threadIdx.x;
    int lane = tid & 63;
    int wv   = tid >> 6;                 // wave 0..3
    int px   = blockIdx.x * 2 + (tid >> 7);
    int b    = px >> 10;

    const float4* E0 = soa;
    const float4* E1 = soa + (size_t)1*NPX;
    const float4* E2 = soa + (size_t)2*NPX;
    const float4* E3 = soa + (size_t)3*NPX;
    const float4* Q0 = soa + (size_t)4*NPX;
    const float4* Q1 = soa + (size_t)5*NPX;
    const float4* Q2 = soa + (size_t)6*NPX;

    float fx = pix[b*16 + 0], fy = pix[b*16 + 5];
    float x0 = pix[b*16 + 2], y0 = pix[b*16 + 6];

    // per-pixel broadcast data (wave-uniform addresses)
    float4 e0 = E0[px], e1 = E1[px], e2 = E2[px], e3 = E3[px];
    float  sei = Q2[px].y;

    const float* Ti = Tm + (size_t)px * 16;
    float R00=Ti[0], R01=Ti[1], R02=Ti[2],  t0=Ti[3];
    float R10=Ti[4], R11=Ti[5], R12=Ti[6],  t1=Ti[7];
    float R20=Ti[8], R21=Ti[9], R22=Ti[10], t2=Ti[11];

    float acc[27];
    #pragma unroll
    for (int t = 0; t < 27; ++t) acc[t] = 0.f;

    int kbase = b * NN + (wv & 1) * (NN/2);
    #pragma unroll 2
    for (int j = 0; j < 8; ++j) {
        int kb = kbase + j*64 + lane;     // consecutive lanes -> consecutive k

        float4 k0 = E0[kb], k1 = E1[kb], k2 = E2[kb], k3 = E3[kb];
        float4 q0 = Q0[kb], q1 = Q1[kb], q2 = Q2[kb];

        // affinity via Gram trick
        float d0 = k0.x*e0.x + k0.y*e0.y + k0.z*e0.z + k0.w*e0.w;
        float d1 = k1.x*e1.x + k1.y*e1.y + k1.z*e1.z + k1.w*e1.w;
        float d2 = k2.x*e2.x + k2.y*e2.y + k2.z*e2.z + k2.w*e2.w;
        float d3 = k3.x*e3.x + k3.y*e3.y + k3.z*e3.z + k3.w*e3.w;
        float dot = (d0 + d1) + (d2 + d3);
        float ssq = fmaxf(sei + q2.y - 2.f*dot, 0.f);
        float aff = __expf(-__builtin_amdgcn_sqrtf(ssq));

        float X = q0.x, Y = q0.y, Z = q0.z;
        float Tx = R00*X + R01*Y + R02*Z + t0;
        float Ty = R10*X + R11*Y + R12*Z + t1;
        float Tz = R20*X + R21*Y + R22*Z + t2;
        float di = __builtin_amdgcn_rcpf(Tz);

        float r0 = fx*Tx*di + x0 - q0.w;
        float r1 = fy*Ty*di + y0 - q1.x;
        float r2 = di            - q1.y;

        float dd = di*di;
        float aJ =  fx*di;
        float cJ = -fx*Tx*dd;
        float eJ =  fy*di;
        float fJ = -fy*Ty*dd;
        float gJ = -dd;

        float J0[6] = { aJ, 0.f, cJ, -cJ*Y,        cJ*X - aJ*Z,  aJ*Y };
        float J1[6] = { 0.f, eJ, fJ,  eJ*Z - fJ*Y, fJ*X,        -eJ*X };
        float J2[6] = { 0.f, 0.f, gJ, -gJ*Y,       gJ*X,         0.f  };

        #pragma unroll
        for (int p = 0; p < 6; ++p)
            acc[21 + p] += J0[p]*r0 + J1[p]*r1 + J2[p]*r2;

        float ww0 = aff*q1.z, ww1 = aff*q1.w, ww2 = aff*q2.x;
        int ix = 0;
        #pragma unroll
        for (int p = 0; p < 6; ++p) {
            float a0 = ww0*J0[p], a1 = ww1*J1[p], a2 = ww2*J2[p];
            #pragma unroll
            for (int q = p; q < 6; ++q) {
                acc[ix] += a0*J0[q] + a1*J1[q] + a2*J2[q];
                ++ix;
            }
        }
    }

    // wave butterfly reduce
    #pragma unroll
    for (int off = 32; off > 0; off >>= 1)
        #pragma unroll
        for (int t = 0; t < 27; ++t)
            acc[t] += __shfl_xor(acc[t], off, 64);

    if (lane == 0)
        #pragma unroll
        for (int t = 0; t < 27; ++t) lds[wv][t] = acc[t];
    __syncthreads();

    // combine the 2 waves of each pixel; wave 0 (resp. 2) writes out
    if ((tid & 64) == 0 && lane < 27) {
        int which = tid >> 7;   // 0 or 1 -> pixel within block
        hws[(size_t)px*27 + lane] =
            lds[which*2][lane] + lds[which*2 + 1][lane];
    }
}

// ---------------------------------------------------------------------------
// Kernel 3: one thread per pixel — 6x6 double Cholesky, expmap, compose.
// ---------------------------------------------------------------------------
__global__ __launch_bounds__(256)
void dse3_solve3(const float* __restrict__ hws,
                 const float* __restrict__ Tm,
                 float* __restrict__ out)
{
    int px = blockIdx.x * 256 + threadIdx.x;
    if (px >= NPX) return;

    const float* Hf = hws + (size_t)px * 27;
    float Hm[21], rh[6];
    #pragma unroll
    for (int t = 0; t < 21; ++t) Hm[t] = Hf[t];
    #pragma unroll
    for (int t = 0; t < 6; ++t)  rh[t] = Hf[21 + t];

    double am[6][6];
    {
        int ix = 0;
        #pragma unroll
        for (int p = 0; p < 6; ++p)
            #pragma unroll
            for (int q = p; q < 6; ++q) {
                am[p][q] = (double)Hm[ix];
                am[q][p] = (double)Hm[ix];
                ++ix;
            }
    }
    double L[6][6];
    #pragma unroll
    for (int p = 0; p < 6; ++p) {
        #pragma unroll
        for (int q = 0; q <= p; ++q) {
            double s = am[p][q];
            #pragma unroll
            for (int r = 0; r < q; ++r) s -= L[p][r]*L[q][r];
            if (q == p) L[p][p] = sqrt(s);
            else        L[p][q] = s / L[q][q];
        }
    }
    double yv[6];
    #pragma unroll
    for (int p = 0; p < 6; ++p) {
        double s = (double)rh[p];
        #pragma unroll
        for (int r = 0; r < p; ++r) s -= L[p][r]*yv[r];
        yv[p] = s / L[p][p];
    }
    double sol[6];
    #pragma unroll
    for (int pi = 5; pi >= 0; --pi) {
        double s = yv[pi];
        #pragma unroll
        for (int r = pi + 1; r < 6; ++r) s -= L[r][pi]*sol[r];
        sol[pi] = s / L[pi][pi];
    }

    double vx = sol[0], vy = sol[1], vz = sol[2];
    double wx = sol[3], wy = sol[4], wz = sol[5];
    double th2 = wx*wx + wy*wy + wz*wz;
    double th  = sqrt(th2);
    double Ae, Be, Ce;
    if (th < 1e-4) {
        Ae = 1.0 - th2/6.0;
        Be = 0.5 - th2/24.0;
        Ce = 1.0/6.0 - th2/120.0;
    } else {
        double sn = sin(th), cn = cos(th);
        Ae = sn/th;
        Be = (1.0 - cn)/th2;
        Ce = (th - sn)/(th2*th);
    }
    double Wh[3][3] = {{0.0,-wz, wy},{ wz,0.0,-wx},{-wy, wx,0.0}};
    double W2[3][3] = {{wx*wx - th2, wx*wy,       wx*wz      },
                       {wx*wy,       wy*wy - th2, wy*wz      },
                       {wx*wz,       wy*wz,       wz*wz - th2}};
    double Rd[3][3], Vd[3][3];
    #pragma unroll
    for (int p = 0; p < 3; ++p)
        #pragma unroll
        for (int q = 0; q < 3; ++q) {
            double idq = (p == q) ? 1.0 : 0.0;
            Rd[p][q] = idq + Ae*Wh[p][q] + Be*W2[p][q];
            Vd[p][q] = idq + Be*Wh[p][q] + Ce*W2[p][q];
        }
    double td[3];
    #pragma unroll
    for (int p = 0; p < 3; ++p)
        td[p] = Vd[p][0]*vx + Vd[p][1]*vy + Vd[p][2]*vz;

    const float* Ti = Tm + (size_t)px * 16;
    float* o = out + (size_t)px * 16;
    #pragma unroll
    for (int p = 0; p < 3; ++p) {
        #pragma unroll
        for (int q = 0; q < 4; ++q) {
            double s = Rd[p][0]*(double)Ti[q]
                     + Rd[p][1]*(double)Ti[4 + q]
                     + Rd[p][2]*(double)Ti[8 + q]
                     + td[p]   *(double)Ti[12 + q];
            o[p*4 + q] = (float)s;
        }
    }
    #pragma unroll
    for (int q = 0; q < 4; ++q) o[12 + q] = Ti[12 + q];
}

extern "C" void kernel_launch(void* const* d_in, const int* in_sizes, int n_in,
                              void* d_out, int out_size, void* d_ws, size_t ws_size,
                              hipStream_t stream) {
    const float* emb = (const float*)d_in[0];  // (B,C,H,W)
    const float* rev = (const float*)d_in[1];  // (B,3,H,W)
    const float* wgt = (const float*)d_in[2];  // (B,3,H,W)
    const float* dep = (const float*)d_in[3];  // (B,1,H,W)
    const float* pix = (const float*)d_in[4];  // (B,4,4)
    const float* Tm  = (const float*)d_in[5];  // (B,H,W,4,4)
    float* out = (float*)d_out;                // (B,H,W,4,4)

    float4* soa = (float4*)d_ws;                       // 7*NPX float4 = 229 KB
    float*  hws = (float*)(soa + (size_t)7*NPX);       // NPX*27 floats = 221 KB

    dse3_prep3 <<<NPX/256, 256, 0, stream>>>(emb, rev, wgt, dep, pix, Tm, soa);
    dse3_accum4<<<NPX/2,   256, 0, stream>>>(soa, pix, Tm, hws);
    dse3_solve3<<<NPX/256, 256, 0, stream>>>(hws, Tm, out);
}

// Round 5
// 33.473 us; speedup vs baseline: 2.5625x; 1.0894x over previous
//
#include <hip/hip_runtime.h>
#include <math.h>

#define BB 2
#define CC 16
#define HH 32
#define WW 32
#define NN (HH*WW)
#define NPX (BB*NN)        // 2048 pixels

// SoA k-record arrays (each float4[NPX]):
//   E0..E3 : embedding e[0..15]
//   Q0     : X, Y, Z, p0      (unprojected xyz; p* = pie(T_k x_k)+rev_k)
//   Q1     : p1, p2, w0, w1
//   Q2     : w2, |e|^2, 0, 0

// ---------------------------------------------------------------------------
// Kernel 1: per-(b,k) precompute into SoA arrays (coalesced writes).
// 32 blocks x 64 threads to spread the latency chains across CUs.
// ---------------------------------------------------------------------------
__global__ __launch_bounds__(64)
void dse3_prep4(const float* __restrict__ emb,
                const float* __restrict__ rev,
                const float* __restrict__ wgt,
                const float* __restrict__ dep,
                const float* __restrict__ pix,
                const float* __restrict__ Tm,
                float4* __restrict__ soa)   // 7 arrays of NPX float4
{
    int idx = blockIdx.x * 64 + threadIdx.x;
    if (idx >= NPX) return;
    int b = idx >> 10;
    int k = idx & (NN - 1);

    float fx = pix[b*16 + 0], fy = pix[b*16 + 5];
    float x0 = pix[b*16 + 2], y0 = pix[b*16 + 6];

    float u = (float)(k & (WW - 1));
    float v = (float)(k >> 5);
    float z = dep[b*NN + k];
    float X = (u - x0) * z / fx;
    float Y = (v - y0) * z / fy;

    const float* T = Tm + (size_t)idx * 16;
    float Tx = T[0]*X + T[1]*Y + T[2]*z  + T[3];
    float Ty = T[4]*X + T[5]*Y + T[6]*z  + T[7];
    float Tz = T[8]*X + T[9]*Y + T[10]*z + T[11];
    float di = 1.0f / Tz;

    float p0 = fx*Tx*di + x0 + rev[(size_t)b*3*NN + 0*NN + k];
    float p1 = fy*Ty*di + y0 + rev[(size_t)b*3*NN + 1*NN + k];
    float p2 = di            + rev[(size_t)b*3*NN + 2*NN + k];
    float w0 = wgt[(size_t)b*3*NN + 0*NN + k];
    float w1 = wgt[(size_t)b*3*NN + 1*NN + k];
    float w2 = wgt[(size_t)b*3*NN + 2*NN + k];

    float se = 0.f;
    float ev[16];
    #pragma unroll
    for (int c = 0; c < 16; ++c) {
        ev[c] = emb[(size_t)b*CC*NN + (size_t)c*NN + k];
        se += ev[c]*ev[c];
    }

    #pragma unroll
    for (int c4 = 0; c4 < 4; ++c4)
        soa[(size_t)c4*NPX + idx] =
            make_float4(ev[c4*4+0], ev[c4*4+1], ev[c4*4+2], ev[c4*4+3]);
    soa[(size_t)4*NPX + idx] = make_float4(X, Y, z, p0);
    soa[(size_t)5*NPX + idx] = make_float4(p1, p2, w0, w1);
    soa[(size_t)6*NPX + idx] = make_float4(w2, se, 0.f, 0.f);
}

// ---------------------------------------------------------------------------
// Kernel 2 (fused accum + solve): block = 256 thr = 4 waves = 2 pixels.
// Each wave covers 512 k's (8 coalesced iters). Butterfly-reduce 27 floats,
// LDS combine per pixel, then ONE thread per pixel does the f32 Cholesky
// solve + expmap + compose inline (tail hidden by other blocks' accum).
// ---------------------------------------------------------------------------
__global__ __launch_bounds__(256)
void dse3_fused(const float4* __restrict__ soa,
                const float* __restrict__ pix,
                const float* __restrict__ Tm,
                float* __restrict__ out)
{
    __shared__ float lds[4][27];
    int tid  = threadIdx.x;
    int lane = tid & 63;
    int wv   = tid >> 6;                 // wave 0..3
    int px   = blockIdx.x * 2 + (tid >> 7);
    int b    = px >> 10;

    const float4* E0 = soa;
    const float4* E1 = soa + (size_t)1*NPX;
    const float4* E2 = soa + (size_t)2*NPX;
    const float4* E3 = soa + (size_t)3*NPX;
    const float4* Q0 = soa + (size_t)4*NPX;
    const float4* Q1 = soa + (size_t)5*NPX;
    const float4* Q2 = soa + (size_t)6*NPX;

    float fx = pix[b*16 + 0], fy = pix[b*16 + 5];
    float x0 = pix[b*16 + 2], y0 = pix[b*16 + 6];

    // per-pixel broadcast data (wave-uniform addresses)
    float4 e0 = E0[px], e1 = E1[px], e2 = E2[px], e3 = E3[px];
    float  sei = Q2[px].y;

    const float* Ti = Tm + (size_t)px * 16;
    float R00=Ti[0], R01=Ti[1], R02=Ti[2],  t0=Ti[3];
    float R10=Ti[4], R11=Ti[5], R12=Ti[6],  t1=Ti[7];
    float R20=Ti[8], R21=Ti[9], R22=Ti[10], t2=Ti[11];

    float acc[27];
    #pragma unroll
    for (int t = 0; t < 27; ++t) acc[t] = 0.f;

    int kbase = b * NN + (wv & 1) * (NN/2);
    #pragma unroll 2
    for (int j = 0; j < 8; ++j) {
        int kb = kbase + j*64 + lane;     // consecutive lanes -> consecutive k

        float4 k0 = E0[kb], k1 = E1[kb], k2 = E2[kb], k3 = E3[kb];
        float4 q0 = Q0[kb], q1 = Q1[kb], q2 = Q2[kb];

        // affinity via Gram trick
        float d0 = k0.x*e0.x + k0.y*e0.y + k0.z*e0.z + k0.w*e0.w;
        float d1 = k1.x*e1.x + k1.y*e1.y + k1.z*e1.z + k1.w*e1.w;
        float d2 = k2.x*e2.x + k2.y*e2.y + k2.z*e2.z + k2.w*e2.w;
        float d3 = k3.x*e3.x + k3.y*e3.y + k3.z*e3.z + k3.w*e3.w;
        float dot = (d0 + d1) + (d2 + d3);
        float ssq = fmaxf(sei + q2.y - 2.f*dot, 0.f);
        float aff = __expf(-__builtin_amdgcn_sqrtf(ssq));

        float X = q0.x, Y = q0.y, Z = q0.z;
        float Tx = R00*X + R01*Y + R02*Z + t0;
        float Ty = R10*X + R11*Y + R12*Z + t1;
        float Tz = R20*X + R21*Y + R22*Z + t2;
        float di = __builtin_amdgcn_rcpf(Tz);

        float aJ =  fx*di;
        float eJ =  fy*di;
        float uu =  aJ*Tx;
        float vv =  eJ*Ty;
        float r0 = uu + x0 - q0.w;
        float r1 = vv + y0 - q1.x;
        float r2 = di      - q1.y;

        float cJ = -uu*di;
        float fJ = -vv*di;
        float gJ = -di*di;

        float J0[6] = { aJ, 0.f, cJ, -cJ*Y,        cJ*X - aJ*Z,  aJ*Y };
        float J1[6] = { 0.f, eJ, fJ,  eJ*Z - fJ*Y, fJ*X,        -eJ*X };
        float J2[6] = { 0.f, 0.f, gJ, -gJ*Y,       gJ*X,         0.f  };

        #pragma unroll
        for (int p = 0; p < 6; ++p)
            acc[21 + p] += J0[p]*r0 + J1[p]*r1 + J2[p]*r2;

        float ww0 = aff*q1.z, ww1 = aff*q1.w, ww2 = aff*q2.x;
        int ix = 0;
        #pragma unroll
        for (int p = 0; p < 6; ++p) {
            float a0 = ww0*J0[p], a1 = ww1*J1[p], a2 = ww2*J2[p];
            #pragma unroll
            for (int q = p; q < 6; ++q) {
                acc[ix] += a0*J0[q] + a1*J1[q] + a2*J2[q];
                ++ix;
            }
        }
    }

    // wave butterfly reduce
    #pragma unroll
    for (int off = 32; off > 0; off >>= 1)
        #pragma unroll
        for (int t = 0; t < 27; ++t)
            acc[t] += __shfl_xor(acc[t], off, 64);

    if (lane == 0)
        #pragma unroll
        for (int t = 0; t < 27; ++t) lds[wv][t] = acc[t];
    __syncthreads();

    // ---- inline solve: one thread per pixel (tid 0 and tid 128) ----
    if ((tid & 127) != 0) return;
    int s = tid >> 7;              // 0 or 1: pixel slot in block

    float Hm[21], rh[6];
    #pragma unroll
    for (int t = 0; t < 21; ++t) Hm[t] = lds[2*s][t] + lds[2*s+1][t];
    #pragma unroll
    for (int t = 0; t < 6; ++t)  rh[t] = lds[2*s][21+t] + lds[2*s+1][21+t];

    // f32 Cholesky (H is SPD weighted-Gram; kappa ~1e4 -> plenty of headroom)
    float am[6][6];
    {
        int ix = 0;
        #pragma unroll
        for (int p = 0; p < 6; ++p)
            #pragma unroll
            for (int q = p; q < 6; ++q) {
                am[p][q] = Hm[ix];
                am[q][p] = Hm[ix];
                ++ix;
            }
    }
    float L[6][6];
    #pragma unroll
    for (int p = 0; p < 6; ++p) {
        #pragma unroll
        for (int q = 0; q <= p; ++q) {
            float sm = am[p][q];
            #pragma unroll
            for (int r = 0; r < q; ++r) sm -= L[p][r]*L[q][r];
            if (q == p) L[p][p] = sqrtf(sm);
            else        L[p][q] = sm / L[q][q];
        }
    }
    float yv[6];
    #pragma unroll
    for (int p = 0; p < 6; ++p) {
        float sm = rh[p];
        #pragma unroll
        for (int r = 0; r < p; ++r) sm -= L[p][r]*yv[r];
        yv[p] = sm / L[p][p];
    }
    float sol[6];
    #pragma unroll
    for (int pi = 5; pi >= 0; --pi) {
        float sm = yv[pi];
        #pragma unroll
        for (int r = pi + 1; r < 6; ++r) sm -= L[r][pi]*sol[r];
        sol[pi] = sm / L[pi][pi];
    }

    // ---- expmap(delta) in f32 ----
    float vx = sol[0], vy = sol[1], vz = sol[2];
    float wx = sol[3], wy = sol[4], wz = sol[5];
    float th2 = wx*wx + wy*wy + wz*wz;
    float th  = sqrtf(th2);
    float Ae, Be, Ce;
    if (th < 1e-4f) {
        Ae = 1.0f - th2*(1.0f/6.0f);
        Be = 0.5f - th2*(1.0f/24.0f);
        Ce = 1.0f/6.0f - th2*(1.0f/120.0f);
    } else {
        float sn = __sinf(th), cn = __cosf(th);
        float ith = 1.0f/th, ith2 = ith*ith;
        Ae = sn*ith;
        Be = (1.0f - cn)*ith2;
        Ce = (th - sn)*ith2*ith;
    }
    float Wh[3][3] = {{0.f,-wz, wy},{ wz,0.f,-wx},{-wy, wx,0.f}};
    float W2[3][3] = {{wx*wx - th2, wx*wy,       wx*wz      },
                      {wx*wy,       wy*wy - th2, wy*wz      },
                      {wx*wz,       wy*wz,       wz*wz - th2}};
    float Rd[3][3], Vd[3][3];
    #pragma unroll
    for (int p = 0; p < 3; ++p)
        #pragma unroll
        for (int q = 0; q < 3; ++q) {
            float idq = (p == q) ? 1.0f : 0.0f;
            Rd[p][q] = idq + Ae*Wh[p][q] + Be*W2[p][q];
            Vd[p][q] = idq + Be*Wh[p][q] + Ce*W2[p][q];
        }
    float td[3];
    #pragma unroll
    for (int p = 0; p < 3; ++p)
        td[p] = Vd[p][0]*vx + Vd[p][1]*vy + Vd[p][2]*vz;

    // ---- out = dT @ Tmat_px ----
    const float* Tp = Tm + (size_t)px * 16;
    float* o = out + (size_t)px * 16;
    #pragma unroll
    for (int p = 0; p < 3; ++p) {
        #pragma unroll
        for (int q = 0; q < 4; ++q) {
            float sm = Rd[p][0]*Tp[q]
                     + Rd[p][1]*Tp[4 + q]
                     + Rd[p][2]*Tp[8 + q]
                     + td[p]   *Tp[12 + q];
            o[p*4 + q] = sm;
        }
    }
    #pragma unroll
    for (int q = 0; q < 4; ++q) o[12 + q] = Tp[12 + q];
}

extern "C" void kernel_launch(void* const* d_in, const int* in_sizes, int n_in,
                              void* d_out, int out_size, void* d_ws, size_t ws_size,
                              hipStream_t stream) {
    const float* emb = (const float*)d_in[0];  // (B,C,H,W)
    const float* rev = (const float*)d_in[1];  // (B,3,H,W)
    const float* wgt = (const float*)d_in[2];  // (B,3,H,W)
    const float* dep = (const float*)d_in[3];  // (B,1,H,W)
    const float* pix = (const float*)d_in[4];  // (B,4,4)
    const float* Tm  = (const float*)d_in[5];  // (B,H,W,4,4)
    float* out = (float*)d_out;                // (B,H,W,4,4)

    float4* soa = (float4*)d_ws;               // 7*NPX float4 = 229 KB

    dse3_prep4<<<NPX/64, 64, 0, stream>>>(emb, rev, wgt, dep, pix, Tm, soa);
    dse3_fused<<<NPX/2, 256, 0, stream>>>(soa, pix, Tm, out);
}